// Round 1
// baseline (629.944 us; speedup 1.0000x reference)
//
#include <hip/hip_runtime.h>

static constexpr int N_NODES = 100000;
static constexpr int D = 64;

__device__ __forceinline__ unsigned f2key(float f) {
    unsigned b = __float_as_uint(f);
    return (b & 0x80000000u) ? ~b : (b | 0x80000000u);
}
__device__ __forceinline__ float key2f(unsigned k) {
    unsigned b = (k & 0x80000000u) ? (k & 0x7fffffffu) : ~k;
    return __uint_as_float(b);
}

// Pass 1: slot[node] = min batch index referencing it; 0xFFFFFFFF = not requested.
__global__ void mark_nodes_kernel(const int* __restrict__ nodes,
                                  unsigned* __restrict__ slot, int B) {
    int b = blockIdx.x * blockDim.x + threadIdx.x;
    if (b < B) atomicMin(&slot[nodes[b]], (unsigned)b);
}

// Pass 2: fused edge MLP -> score, plus per-dst float max (ordered-uint atomicMax).
// One wave per (flagged) edge. Weights staged in LDS.
__global__ __launch_bounds__(256) void score_kernel(
    const float* __restrict__ embed_u, const float* __restrict__ rep,
    const int* __restrict__ dst,
    const float* __restrict__ W1, const float* __restrict__ b1,
    const float* __restrict__ W2, const float* __restrict__ b2,
    const float* __restrict__ W3, const float* __restrict__ b3,
    const unsigned* __restrict__ slot,
    float* __restrict__ score, unsigned* __restrict__ seg_max_key, int E)
{
    __shared__ float W1s[128 * 64];
    __shared__ float W2s[64 * 64];
    __shared__ float W3s[64], b1s[64], b2s[64];
    for (int i = threadIdx.x; i < 128 * 64; i += blockDim.x) W1s[i] = W1[i];
    for (int i = threadIdx.x; i < 64 * 64; i += blockDim.x) W2s[i] = W2[i];
    if (threadIdx.x < 64) {
        W3s[threadIdx.x] = W3[threadIdx.x];
        b1s[threadIdx.x] = b1[threadIdx.x];
        b2s[threadIdx.x] = b2[threadIdx.x];
    }
    __syncthreads();
    const float bias3 = b3[0];
    const int lane = threadIdx.x & 63;
    const int wid = (blockIdx.x * blockDim.x + threadIdx.x) >> 6;
    const int nw = (gridDim.x * blockDim.x) >> 6;
    for (int e = wid; e < E; e += nw) {
        const int d = dst[e];                    // wave-uniform -> s_load
        if (slot[d] == 0xFFFFFFFFu) continue;    // wave-uniform skip
        const float xu = embed_u[(size_t)e * D + lane];
        const float xr = rep[(size_t)e * D + lane];
        // h1[lane] = relu(b1 + sum_j x[j] * W1[j][lane])
        float acc = b1s[lane];
        #pragma unroll
        for (int j = 0; j < 64; ++j)
            acc = fmaf(__shfl(xu, j), W1s[j * 64 + lane], acc);
        #pragma unroll
        for (int j = 0; j < 64; ++j)
            acc = fmaf(__shfl(xr, j), W1s[(64 + j) * 64 + lane], acc);
        const float h1 = fmaxf(acc, 0.f);
        // h2[lane] = relu(b2 + sum_j h1[j] * W2[j][lane])
        float acc2 = b2s[lane];
        #pragma unroll
        for (int j = 0; j < 64; ++j)
            acc2 = fmaf(__shfl(h1, j), W2s[j * 64 + lane], acc2);
        const float h2 = fmaxf(acc2, 0.f);
        // score = b3 + sum_k h2[k] * W3[k]
        float p = h2 * W3s[lane];
        #pragma unroll
        for (int off = 32; off > 0; off >>= 1) p += __shfl_xor(p, off);
        const float sc = p + bias3;
        if (lane == 0) {
            score[e] = sc;
            atomicMax(&seg_max_key[d], f2key(sc));
        }
    }
}

// Pass 3: e = exp(score - seg_max[dst]); seg_sum[dst] += e.  (score overwritten with e)
__global__ void exp_kernel(const int* __restrict__ dst,
                           const unsigned* __restrict__ slot,
                           const unsigned* __restrict__ seg_max_key,
                           float* __restrict__ score,
                           float* __restrict__ seg_sum, int E) {
    int e = blockIdx.x * blockDim.x + threadIdx.x;
    if (e >= E) return;
    int d = dst[e];
    if (slot[d] == 0xFFFFFFFFu) return;
    float m = key2f(seg_max_key[d]);
    float ev = __expf(score[e] - m);
    score[e] = ev;
    atomicAdd(&seg_sum[d], ev);
}

// Pass 4: out[slot[dst]] += embed_u[e] * (e / seg_sum[dst]).  One wave per edge.
__global__ __launch_bounds__(256) void agg_kernel(
    const float* __restrict__ embed_u, const int* __restrict__ dst,
    const unsigned* __restrict__ slot,
    const float* __restrict__ score, const float* __restrict__ seg_sum,
    float* __restrict__ out, int E) {
    const int lane = threadIdx.x & 63;
    const int wid = (blockIdx.x * blockDim.x + threadIdx.x) >> 6;
    const int nw = (gridDim.x * blockDim.x) >> 6;
    for (int e = wid; e < E; e += nw) {
        const int d = dst[e];
        const unsigned s = slot[d];
        if (s == 0xFFFFFFFFu) continue;
        const float att = score[e] / seg_sum[d];
        const float v = embed_u[(size_t)e * D + lane] * att;
        atomicAdd(&out[(size_t)s * D + lane], v);
    }
}

// Pass 5: replicate rows for duplicate batch entries.
__global__ void repl_kernel(const int* __restrict__ nodes,
                            const unsigned* __restrict__ slot,
                            float* __restrict__ out, int B) {
    int t = blockIdx.x * blockDim.x + threadIdx.x;
    int b = t >> 6, lane = t & 63;
    if (b >= B) return;
    unsigned s = slot[nodes[b]];
    if (s != (unsigned)b) out[(size_t)b * D + lane] = out[(size_t)s * D + lane];
}

extern "C" void kernel_launch(void* const* d_in, const int* in_sizes, int n_in,
                              void* d_out, int out_size, void* d_ws, size_t ws_size,
                              hipStream_t stream) {
    const float* embed_u = (const float*)d_in[0];
    const float* rep     = (const float*)d_in[1];
    const int*   dst     = (const int*)d_in[2];
    const int*   nodes   = (const int*)d_in[3];
    const float* W1      = (const float*)d_in[4];
    const float* b1      = (const float*)d_in[5];
    const float* W2      = (const float*)d_in[6];
    const float* b2      = (const float*)d_in[7];
    const float* W3      = (const float*)d_in[8];
    const float* b3      = (const float*)d_in[9];
    float* out = (float*)d_out;
    const int E = in_sizes[2];
    const int B = in_sizes[3];

    char* ws = (char*)d_ws;
    unsigned* slot   = (unsigned*)(ws);                  // N*4 = 400000 B
    unsigned* segmax = (unsigned*)(ws + 512 * 1024);     // N*4
    float*    segsum = (float*)   (ws + 1024 * 1024);    // N*4
    float*    score  = (float*)   (ws + 1536 * 1024);    // E*4 = 4 MB

    hipMemsetAsync(slot, 0xFF, (size_t)N_NODES * 4, stream);
    hipMemsetAsync(ws + 512 * 1024, 0, 1024 * 1024, stream);   // segmax + segsum
    hipMemsetAsync(out, 0, (size_t)out_size * 4, stream);

    mark_nodes_kernel<<<(B + 255) / 256, 256, 0, stream>>>(nodes, slot, B);

    score_kernel<<<2048, 256, 0, stream>>>(embed_u, rep, dst, W1, b1, W2, b2, W3, b3,
                                           slot, score, segmax, E);

    exp_kernel<<<(E + 255) / 256, 256, 0, stream>>>(dst, slot, segmax, score, segsum, E);

    agg_kernel<<<2048, 256, 0, stream>>>(embed_u, dst, slot, score, segsum, out, E);

    repl_kernel<<<(B * D + 255) / 256, 256, 0, stream>>>(nodes, slot, out, B);
}

// Round 2
// 280.869 us; speedup vs baseline: 2.2428x; 2.2428x over previous
//
#include <hip/hip_runtime.h>

static constexpr int N_NODES = 100000;
static constexpr int D = 64;

typedef float  f32x4 __attribute__((ext_vector_type(4)));
typedef short  s16x8 __attribute__((ext_vector_type(8)));

__device__ __forceinline__ unsigned f2key(float f) {
    unsigned b = __float_as_uint(f);
    return (b & 0x80000000u) ? ~b : (b | 0x80000000u);
}
__device__ __forceinline__ float key2f(unsigned k) {
    unsigned b = (k & 0x80000000u) ? (k & 0x7fffffffu) : ~k;
    return __uint_as_float(b);
}
__device__ __forceinline__ unsigned short f2bf(float f) {
    unsigned u = __float_as_uint(f);
    return (unsigned short)((u + 0x7FFFu + ((u >> 16) & 1u)) >> 16);
}

// Pass 1: slot[node] = min batch index referencing it; 0xFFFFFFFF = not requested.
__global__ void mark_nodes_kernel(const int* __restrict__ nodes,
                                  unsigned* __restrict__ slot, int B) {
    int b = blockIdx.x * blockDim.x + threadIdx.x;
    if (b < B) atomicMin(&slot[nodes[b]], (unsigned)b);
}

// Pass 2: compact flagged edges (dst is a requested node) into elist/dstc.
__global__ void compact_kernel(const int* __restrict__ dst,
                               const unsigned* __restrict__ slot,
                               unsigned* __restrict__ count,
                               int* __restrict__ elist, int* __restrict__ dstc, int E) {
    int e = blockIdx.x * blockDim.x + threadIdx.x;
    if (e >= E) return;
    int d = dst[e];
    if (slot[d] != 0xFFFFFFFFu) {
        unsigned pos = atomicAdd(count, 1u);   // wave-aggregated by compiler
        elist[pos] = e;
        dstc[pos] = d;
    }
}

// Pass 3: MFMA MLP over compacted edges -> score, + per-dst ordered-uint atomicMax.
// Each wave owns a 16-edge tile; block stages bf16-transposed W1/W2 once.
__global__ __launch_bounds__(256) void mlp_score_kernel(
    const float* __restrict__ embed_u, const float* __restrict__ rep,
    const float* __restrict__ W1, const float* __restrict__ b1,
    const float* __restrict__ W2, const float* __restrict__ b2,
    const float* __restrict__ W3, const float* __restrict__ b3,
    const unsigned* __restrict__ count,
    const int* __restrict__ elist, const int* __restrict__ dstc,
    float* __restrict__ score_c, unsigned* __restrict__ seg_max_key)
{
    // W1t[c][k]: 64 rows x 136 (128 used) bf16 ; W2t[c][k]: 64 x 72 (64 used)
    __shared__ __align__(16) short W1t[64 * 136];
    __shared__ __align__(16) short W2t[64 * 72];
    __shared__ __align__(16) short Xbf[4][16 * 136];  // per-wave: 16 edges x 128 (pad 136)
    __shared__ __align__(16) short Hs[4][16 * 72];    // per-wave: 16 edges x 64 (pad 72)

    const int tid = threadIdx.x;
    // stage W1 (128x64) -> W1t[c][k] bf16
    for (int i = tid; i < 128 * 64; i += 256) {
        int k = i >> 6, c = i & 63;
        W1t[c * 136 + k] = (short)f2bf(W1[i]);
    }
    // stage W2 (64x64) -> W2t[c][k] bf16
    for (int i = tid; i < 64 * 64; i += 256) {
        int k = i >> 6, c = i & 63;
        W2t[c * 72 + k] = (short)f2bf(W2[i]);
    }
    __syncthreads();

    const int cnt = (int)*count;
    if (cnt == 0) return;
    const int ntiles = (cnt + 15) >> 4;
    const int ntg = (ntiles + 3) >> 2;

    const int wid = tid >> 6;
    const int lane = tid & 63;
    const int cl = lane & 15;     // A-row / B-col within tile
    const int quad = lane >> 4;   // k-block selector

    // per-lane bias / W3 registers
    float b1v[4], b2v[4], w3v[4];
    #pragma unroll
    for (int ct = 0; ct < 4; ++ct) {
        b1v[ct] = b1[ct * 16 + cl];
        b2v[ct] = b2[ct * 16 + cl];
        w3v[ct] = W3[ct * 16 + cl];
    }
    const float b3s = b3[0];

    short* Xw = Xbf[wid];
    short* Hw = Hs[wid];

    for (int tg = blockIdx.x; tg < ntg; tg += gridDim.x) {
        const int tile = tg * 4 + wid;
        if (tile >= ntiles) break;
        const int gbase = tile << 4;

        // ---- stage X: lane (cl=row, quad=16-float chunk) gathers + converts ----
        const int er = elist[min(gbase + cl, cnt - 1)];
        const float4* eb = (const float4*)(embed_u + (size_t)er * D);
        const float4* rp = (const float4*)(rep + (size_t)er * D);
        #pragma unroll
        for (int src = 0; src < 2; ++src) {
            const float4* pbase = src ? rp : eb;
            const int kofs = src ? 64 : 0;
            #pragma unroll
            for (int h = 0; h < 2; ++h) {  // two short8 writes of 8 bf16 each
                float4 v0 = pbase[quad * 4 + h * 2 + 0];
                float4 v1 = pbase[quad * 4 + h * 2 + 1];
                s16x8 pk;
                pk[0] = (short)f2bf(v0.x); pk[1] = (short)f2bf(v0.y);
                pk[2] = (short)f2bf(v0.z); pk[3] = (short)f2bf(v0.w);
                pk[4] = (short)f2bf(v1.x); pk[5] = (short)f2bf(v1.y);
                pk[6] = (short)f2bf(v1.z); pk[7] = (short)f2bf(v1.w);
                *(s16x8*)&Xw[cl * 136 + kofs + quad * 16 + h * 8] = pk;
            }
        }

        // ---- layer 1: [16,128] x [128,64] ----
        f32x4 acc[4];
        #pragma unroll
        for (int ct = 0; ct < 4; ++ct)
            acc[ct] = (f32x4){b1v[ct], b1v[ct], b1v[ct], b1v[ct]};
        #pragma unroll
        for (int ks = 0; ks < 4; ++ks) {
            s16x8 af = *(const s16x8*)&Xw[cl * 136 + ks * 32 + quad * 8];
            #pragma unroll
            for (int ct = 0; ct < 4; ++ct) {
                s16x8 bf = *(const s16x8*)&W1t[(ct * 16 + cl) * 136 + ks * 32 + quad * 8];
                acc[ct] = __builtin_amdgcn_mfma_f32_16x16x32_bf16(af, bf, acc[ct], 0, 0, 0);
            }
        }
        // relu -> bf16 -> Hs (row-major [16][72]); C/D: col=cl, row=quad*4+reg
        #pragma unroll
        for (int ct = 0; ct < 4; ++ct)
            #pragma unroll
            for (int reg = 0; reg < 4; ++reg)
                Hw[(quad * 4 + reg) * 72 + ct * 16 + cl] =
                    (short)f2bf(fmaxf(acc[ct][reg], 0.f));

        // ---- layer 2: [16,64] x [64,64] ----
        f32x4 acc2[4];
        #pragma unroll
        for (int ct = 0; ct < 4; ++ct)
            acc2[ct] = (f32x4){b2v[ct], b2v[ct], b2v[ct], b2v[ct]};
        #pragma unroll
        for (int ks = 0; ks < 2; ++ks) {
            s16x8 af = *(const s16x8*)&Hw[cl * 72 + ks * 32 + quad * 8];
            #pragma unroll
            for (int ct = 0; ct < 4; ++ct) {
                s16x8 bf = *(const s16x8*)&W2t[(ct * 16 + cl) * 72 + ks * 32 + quad * 8];
                acc2[ct] = __builtin_amdgcn_mfma_f32_16x16x32_bf16(af, bf, acc2[ct], 0, 0, 0);
            }
        }

        // ---- layer 3: score[row] = b3 + sum_c relu(h2[row][c]) * W3[c] ----
        float p[4];
        #pragma unroll
        for (int reg = 0; reg < 4; ++reg) {
            float s = 0.f;
            #pragma unroll
            for (int ct = 0; ct < 4; ++ct)
                s += fmaxf(acc2[ct][reg], 0.f) * w3v[ct];
            p[reg] = s;
        }
        #pragma unroll
        for (int off = 1; off < 16; off <<= 1)
            #pragma unroll
            for (int reg = 0; reg < 4; ++reg)
                p[reg] += __shfl_xor(p[reg], off);

        if (cl == 0) {
            #pragma unroll
            for (int reg = 0; reg < 4; ++reg) {
                int gi = gbase + quad * 4 + reg;
                if (gi < cnt) {
                    float sc = p[reg] + b3s;
                    score_c[gi] = sc;
                    atomicMax(&seg_max_key[dstc[gi]], f2key(sc));
                }
            }
        }
    }
}

// Pass 4: e = exp(score - seg_max[dst]); seg_sum[dst] += e. (score_c overwritten)
__global__ void expsum_kernel(const unsigned* __restrict__ count,
                              const int* __restrict__ dstc,
                              const unsigned* __restrict__ seg_max_key,
                              float* __restrict__ score_c,
                              float* __restrict__ seg_sum) {
    const int cnt = (int)*count;
    const int stride = gridDim.x * blockDim.x;
    for (int i = blockIdx.x * blockDim.x + threadIdx.x; i < cnt; i += stride) {
        int d = dstc[i];
        float ev = __expf(score_c[i] - key2f(seg_max_key[d]));
        score_c[i] = ev;
        atomicAdd(&seg_sum[d], ev);
    }
}

// Pass 5: out[slot[dst]] += embed_u[e] * att. One wave per compacted edge.
__global__ __launch_bounds__(256) void agg_kernel(
    const float* __restrict__ embed_u,
    const unsigned* __restrict__ count,
    const int* __restrict__ elist, const int* __restrict__ dstc,
    const unsigned* __restrict__ slot,
    const float* __restrict__ score_c, const float* __restrict__ seg_sum,
    float* __restrict__ out) {
    const int cnt = (int)*count;
    const int lane = threadIdx.x & 63;
    const int wid = (blockIdx.x * blockDim.x + threadIdx.x) >> 6;
    const int nw = (gridDim.x * blockDim.x) >> 6;
    for (int i = wid; i < cnt; i += nw) {
        const int e = elist[i];
        const int d = dstc[i];
        const float att = score_c[i] / seg_sum[d];
        const unsigned s = slot[d];
        const float v = embed_u[(size_t)e * D + lane] * att;
        atomicAdd(&out[(size_t)s * D + lane], v);
    }
}

// Pass 6: replicate rows for duplicate batch entries.
__global__ void repl_kernel(const int* __restrict__ nodes,
                            const unsigned* __restrict__ slot,
                            float* __restrict__ out, int B) {
    int t = blockIdx.x * blockDim.x + threadIdx.x;
    int b = t >> 6, lane = t & 63;
    if (b >= B) return;
    unsigned s = slot[nodes[b]];
    if (s != (unsigned)b) out[(size_t)b * D + lane] = out[(size_t)s * D + lane];
}

extern "C" void kernel_launch(void* const* d_in, const int* in_sizes, int n_in,
                              void* d_out, int out_size, void* d_ws, size_t ws_size,
                              hipStream_t stream) {
    const float* embed_u = (const float*)d_in[0];
    const float* rep     = (const float*)d_in[1];
    const int*   dst     = (const int*)d_in[2];
    const int*   nodes   = (const int*)d_in[3];
    const float* W1      = (const float*)d_in[4];
    const float* b1      = (const float*)d_in[5];
    const float* W2      = (const float*)d_in[6];
    const float* b2      = (const float*)d_in[7];
    const float* W3      = (const float*)d_in[8];
    const float* b3      = (const float*)d_in[9];
    float* out = (float*)d_out;
    const int E = in_sizes[2];
    const int B = in_sizes[3];

    char* ws = (char*)d_ws;
    unsigned* slot    = (unsigned*)(ws);                        // 400 KB region
    unsigned* segmax  = (unsigned*)(ws + 512 * 1024);
    float*    segsum  = (float*)   (ws + 1024 * 1024);
    unsigned* count   = (unsigned*)(ws + 1536 * 1024);
    int*      elist   = (int*)     (ws + (size_t)2  * 1024 * 1024);  // E*4
    int*      dstc    = (int*)     (ws + (size_t)6  * 1024 * 1024);  // E*4
    float*    score_c = (float*)   (ws + (size_t)10 * 1024 * 1024);  // E*4

    hipMemsetAsync(slot, 0xFF, (size_t)N_NODES * 4, stream);
    hipMemsetAsync(ws + 512 * 1024, 0, 1024 * 1024 + 4096, stream);  // segmax+segsum+count
    hipMemsetAsync(out, 0, (size_t)out_size * 4, stream);

    mark_nodes_kernel<<<(B + 255) / 256, 256, 0, stream>>>(nodes, slot, B);

    compact_kernel<<<(E + 255) / 256, 256, 0, stream>>>(dst, slot, count, elist, dstc, E);

    mlp_score_kernel<<<1024, 256, 0, stream>>>(embed_u, rep, W1, b1, W2, b2, W3, b3,
                                               count, elist, dstc, score_c, segmax);

    expsum_kernel<<<512, 256, 0, stream>>>(count, dstc, segmax, score_c, segsum);

    agg_kernel<<<2048, 256, 0, stream>>>(embed_u, count, elist, dstc, slot,
                                         score_c, segsum, out);

    repl_kernel<<<(B * D + 255) / 256, 256, 0, stream>>>(nodes, slot, out, B);
}

// Round 3
// 124.663 us; speedup vs baseline: 5.0532x; 2.2530x over previous
//
#include <hip/hip_runtime.h>

static constexpr int N_NODES = 100000;
static constexpr int D = 64;
static constexpr int CHUNK = 4096;   // edges per compaction block

typedef float  f32x4 __attribute__((ext_vector_type(4)));
typedef short  s16x8 __attribute__((ext_vector_type(8)));

__device__ __forceinline__ unsigned f2key(float f) {
    unsigned b = __float_as_uint(f);
    return (b & 0x80000000u) ? ~b : (b | 0x80000000u);
}
__device__ __forceinline__ float key2f(unsigned k) {
    unsigned b = (k & 0x80000000u) ? (k & 0x7fffffffu) : ~k;
    return __uint_as_float(b);
}
__device__ __forceinline__ unsigned short f2bf(float f) {
    unsigned u = __float_as_uint(f);
    return (unsigned short)((u + 0x7FFFu + ((u >> 16) & 1u)) >> 16);
}

// Pass 1: slot[node] = min batch index referencing it; 0xFFFFFFFF = not requested.
__global__ void mark_nodes_kernel(const int* __restrict__ nodes,
                                  unsigned* __restrict__ slot, int B) {
    int b = blockIdx.x * blockDim.x + threadIdx.x;
    if (b < B) atomicMin(&slot[nodes[b]], (unsigned)b);
}

// Pass 2a: per-block flagged-edge counts (no atomics).
__global__ __launch_bounds__(256) void count_kernel(
    const int* __restrict__ dst, const unsigned* __restrict__ slot,
    unsigned* __restrict__ blockCount, int E) {
    const int base = blockIdx.x * CHUNK;
    unsigned c = 0;
    for (int it = 0; it < CHUNK; it += 256) {
        int e = base + it + threadIdx.x;
        if (e < E && slot[dst[e]] != 0xFFFFFFFFu) c++;
    }
    #pragma unroll
    for (int off = 32; off; off >>= 1) c += __shfl_down(c, off);
    __shared__ unsigned ws[4];
    if ((threadIdx.x & 63) == 0) ws[threadIdx.x >> 6] = c;
    __syncthreads();
    if (threadIdx.x == 0)
        blockCount[blockIdx.x] = ws[0] + ws[1] + ws[2] + ws[3];
}

// Pass 2b: single-block exclusive scan of block counts; writes grand total.
__global__ __launch_bounds__(256) void scan_kernel(
    const unsigned* __restrict__ blockCount, unsigned* __restrict__ blockOff,
    unsigned* __restrict__ total, int n) {
    __shared__ unsigned run;
    __shared__ unsigned wsum[4];
    if (threadIdx.x == 0) run = 0;
    __syncthreads();
    for (int base = 0; base < n; base += 256) {
        int i = base + threadIdx.x;
        unsigned v = (i < n) ? blockCount[i] : 0;
        unsigned p = v;
        #pragma unroll
        for (int off = 1; off < 64; off <<= 1) {
            unsigned t = __shfl_up(p, off);
            if ((threadIdx.x & 63) >= off) p += t;
        }
        if ((threadIdx.x & 63) == 63) wsum[threadIdx.x >> 6] = p;
        __syncthreads();
        unsigned woff = 0;
        for (int w = 0; w < (threadIdx.x >> 6); ++w) woff += wsum[w];
        if (i < n) blockOff[i] = run + woff + p - v;
        __syncthreads();
        if (threadIdx.x == 0) run += wsum[0] + wsum[1] + wsum[2] + wsum[3];
        __syncthreads();
    }
    if (threadIdx.x == 0) *total = run;
}

// Pass 2c: write compacted edges at deterministic offsets.
__global__ __launch_bounds__(256) void fill_kernel(
    const int* __restrict__ dst, const unsigned* __restrict__ slot,
    const unsigned* __restrict__ blockOff,
    int* __restrict__ elist, int* __restrict__ dstc, int E) {
    __shared__ unsigned iterbase;
    __shared__ unsigned wsum[4];
    const int base = blockIdx.x * CHUNK;
    if (threadIdx.x == 0) iterbase = blockOff[blockIdx.x];
    __syncthreads();
    const int lane = threadIdx.x & 63;
    const int w = threadIdx.x >> 6;
    for (int it = 0; it < CHUNK; it += 256) {
        int e = base + it + threadIdx.x;
        int d = (e < E) ? dst[e] : 0;
        bool flag = (e < E) && (slot[d] != 0xFFFFFFFFu);
        unsigned long long m = __ballot(flag);
        unsigned lower = __popcll(m & ((1ull << lane) - 1ull));
        if (lane == 0) wsum[w] = (unsigned)__popcll(m);
        __syncthreads();
        unsigned woff = 0;
        for (int ww = 0; ww < w; ++ww) woff += wsum[ww];
        if (flag) {
            unsigned pos = iterbase + woff + lower;
            elist[pos] = e;
            dstc[pos] = d;
        }
        __syncthreads();
        if (threadIdx.x == 0) iterbase += wsum[0] + wsum[1] + wsum[2] + wsum[3];
        __syncthreads();
    }
}

// Pass 3: MFMA MLP over compacted edges -> score, + per-dst ordered-uint atomicMax.
__global__ __launch_bounds__(256) void mlp_score_kernel(
    const float* __restrict__ embed_u, const float* __restrict__ rep,
    const float* __restrict__ W1, const float* __restrict__ b1,
    const float* __restrict__ W2, const float* __restrict__ b2,
    const float* __restrict__ W3, const float* __restrict__ b3,
    const unsigned* __restrict__ count,
    const int* __restrict__ elist, const int* __restrict__ dstc,
    float* __restrict__ score_c, unsigned* __restrict__ seg_max_key)
{
    __shared__ __align__(16) short W1t[64 * 136];
    __shared__ __align__(16) short W2t[64 * 72];
    __shared__ __align__(16) short Xbf[4][16 * 136];
    __shared__ __align__(16) short Hs[4][16 * 72];

    const int tid = threadIdx.x;
    for (int i = tid; i < 128 * 64; i += 256) {
        int k = i >> 6, c = i & 63;
        W1t[c * 136 + k] = (short)f2bf(W1[i]);
    }
    for (int i = tid; i < 64 * 64; i += 256) {
        int k = i >> 6, c = i & 63;
        W2t[c * 72 + k] = (short)f2bf(W2[i]);
    }
    __syncthreads();

    const int cnt = (int)*count;
    if (cnt == 0) return;
    const int ntiles = (cnt + 15) >> 4;
    const int ntg = (ntiles + 3) >> 2;

    const int wid = tid >> 6;
    const int lane = tid & 63;
    const int cl = lane & 15;
    const int quad = lane >> 4;

    float b1v[4], b2v[4], w3v[4];
    #pragma unroll
    for (int ct = 0; ct < 4; ++ct) {
        b1v[ct] = b1[ct * 16 + cl];
        b2v[ct] = b2[ct * 16 + cl];
        w3v[ct] = W3[ct * 16 + cl];
    }
    const float b3s = b3[0];

    short* Xw = Xbf[wid];
    short* Hw = Hs[wid];

    for (int tg = blockIdx.x; tg < ntg; tg += gridDim.x) {
        const int tile = tg * 4 + wid;
        if (tile >= ntiles) break;
        const int gbase = tile << 4;

        const int er = elist[min(gbase + cl, cnt - 1)];
        const float4* eb = (const float4*)(embed_u + (size_t)er * D);
        const float4* rp = (const float4*)(rep + (size_t)er * D);
        #pragma unroll
        for (int src = 0; src < 2; ++src) {
            const float4* pbase = src ? rp : eb;
            const int kofs = src ? 64 : 0;
            #pragma unroll
            for (int h = 0; h < 2; ++h) {
                float4 v0 = pbase[quad * 4 + h * 2 + 0];
                float4 v1 = pbase[quad * 4 + h * 2 + 1];
                s16x8 pk;
                pk[0] = (short)f2bf(v0.x); pk[1] = (short)f2bf(v0.y);
                pk[2] = (short)f2bf(v0.z); pk[3] = (short)f2bf(v0.w);
                pk[4] = (short)f2bf(v1.x); pk[5] = (short)f2bf(v1.y);
                pk[6] = (short)f2bf(v1.z); pk[7] = (short)f2bf(v1.w);
                *(s16x8*)&Xw[cl * 136 + kofs + quad * 16 + h * 8] = pk;
            }
        }

        f32x4 acc[4];
        #pragma unroll
        for (int ct = 0; ct < 4; ++ct)
            acc[ct] = (f32x4){b1v[ct], b1v[ct], b1v[ct], b1v[ct]};
        #pragma unroll
        for (int ks = 0; ks < 4; ++ks) {
            s16x8 af = *(const s16x8*)&Xw[cl * 136 + ks * 32 + quad * 8];
            #pragma unroll
            for (int ct = 0; ct < 4; ++ct) {
                s16x8 bf = *(const s16x8*)&W1t[(ct * 16 + cl) * 136 + ks * 32 + quad * 8];
                acc[ct] = __builtin_amdgcn_mfma_f32_16x16x32_bf16(af, bf, acc[ct], 0, 0, 0);
            }
        }
        #pragma unroll
        for (int ct = 0; ct < 4; ++ct)
            #pragma unroll
            for (int reg = 0; reg < 4; ++reg)
                Hw[(quad * 4 + reg) * 72 + ct * 16 + cl] =
                    (short)f2bf(fmaxf(acc[ct][reg], 0.f));

        f32x4 acc2[4];
        #pragma unroll
        for (int ct = 0; ct < 4; ++ct)
            acc2[ct] = (f32x4){b2v[ct], b2v[ct], b2v[ct], b2v[ct]};
        #pragma unroll
        for (int ks = 0; ks < 2; ++ks) {
            s16x8 af = *(const s16x8*)&Hw[cl * 72 + ks * 32 + quad * 8];
            #pragma unroll
            for (int ct = 0; ct < 4; ++ct) {
                s16x8 bf = *(const s16x8*)&W2t[(ct * 16 + cl) * 72 + ks * 32 + quad * 8];
                acc2[ct] = __builtin_amdgcn_mfma_f32_16x16x32_bf16(af, bf, acc2[ct], 0, 0, 0);
            }
        }

        float p[4];
        #pragma unroll
        for (int reg = 0; reg < 4; ++reg) {
            float s = 0.f;
            #pragma unroll
            for (int ct = 0; ct < 4; ++ct)
                s += fmaxf(acc2[ct][reg], 0.f) * w3v[ct];
            p[reg] = s;
        }
        #pragma unroll
        for (int off = 1; off < 16; off <<= 1)
            #pragma unroll
            for (int reg = 0; reg < 4; ++reg)
                p[reg] += __shfl_xor(p[reg], off);

        if (cl == 0) {
            #pragma unroll
            for (int reg = 0; reg < 4; ++reg) {
                int gi = gbase + quad * 4 + reg;
                if (gi < cnt) {
                    float sc = p[reg] + b3s;
                    score_c[gi] = sc;
                    atomicMax(&seg_max_key[dstc[gi]], f2key(sc));
                }
            }
        }
    }
}

// Pass 4: e = exp(score - seg_max[dst]); seg_sum[dst] += e. (score_c overwritten)
__global__ void expsum_kernel(const unsigned* __restrict__ count,
                              const int* __restrict__ dstc,
                              const unsigned* __restrict__ seg_max_key,
                              float* __restrict__ score_c,
                              float* __restrict__ seg_sum) {
    const int cnt = (int)*count;
    const int stride = gridDim.x * blockDim.x;
    for (int i = blockIdx.x * blockDim.x + threadIdx.x; i < cnt; i += stride) {
        int d = dstc[i];
        float ev = __expf(score_c[i] - key2f(seg_max_key[d]));
        score_c[i] = ev;
        atomicAdd(&seg_sum[d], ev);
    }
}

// Pass 5: out[slot[dst]] += embed_u[e] * att. One wave per compacted edge.
__global__ __launch_bounds__(256) void agg_kernel(
    const float* __restrict__ embed_u,
    const unsigned* __restrict__ count,
    const int* __restrict__ elist, const int* __restrict__ dstc,
    const unsigned* __restrict__ slot,
    const float* __restrict__ score_c, const float* __restrict__ seg_sum,
    float* __restrict__ out) {
    const int cnt = (int)*count;
    const int lane = threadIdx.x & 63;
    const int wid = (blockIdx.x * blockDim.x + threadIdx.x) >> 6;
    const int nw = (gridDim.x * blockDim.x) >> 6;
    for (int i = wid; i < cnt; i += nw) {
        const int e = elist[i];
        const int d = dstc[i];
        const float att = score_c[i] / seg_sum[d];
        const unsigned s = slot[d];
        const float v = embed_u[(size_t)e * D + lane] * att;
        atomicAdd(&out[(size_t)s * D + lane], v);
    }
}

// Pass 6: replicate rows for duplicate batch entries.
__global__ void repl_kernel(const int* __restrict__ nodes,
                            const unsigned* __restrict__ slot,
                            float* __restrict__ out, int B) {
    int t = blockIdx.x * blockDim.x + threadIdx.x;
    int b = t >> 6, lane = t & 63;
    if (b >= B) return;
    unsigned s = slot[nodes[b]];
    if (s != (unsigned)b) out[(size_t)b * D + lane] = out[(size_t)s * D + lane];
}

extern "C" void kernel_launch(void* const* d_in, const int* in_sizes, int n_in,
                              void* d_out, int out_size, void* d_ws, size_t ws_size,
                              hipStream_t stream) {
    const float* embed_u = (const float*)d_in[0];
    const float* rep     = (const float*)d_in[1];
    const int*   dst     = (const int*)d_in[2];
    const int*   nodes   = (const int*)d_in[3];
    const float* W1      = (const float*)d_in[4];
    const float* b1      = (const float*)d_in[5];
    const float* W2      = (const float*)d_in[6];
    const float* b2      = (const float*)d_in[7];
    const float* W3      = (const float*)d_in[8];
    const float* b3      = (const float*)d_in[9];
    float* out = (float*)d_out;
    const int E = in_sizes[2];
    const int B = in_sizes[3];
    const int NBLK = (E + CHUNK - 1) / CHUNK;

    char* ws = (char*)d_ws;
    unsigned* slot    = (unsigned*)(ws);                             // N*4
    unsigned* segmax  = (unsigned*)(ws + 512 * 1024);                // N*4
    float*    segsum  = (float*)   (ws + 1024 * 1024);               // N*4
    unsigned* count   = (unsigned*)(ws + 1536 * 1024);               // 4
    unsigned* bcount  = (unsigned*)(ws + 1536 * 1024 + 4096);        // NBLK*4
    unsigned* boff    = (unsigned*)(ws + 1536 * 1024 + 64 * 1024);   // NBLK*4
    int*      elist   = (int*)     (ws + (size_t)2  * 1024 * 1024);  // E*4
    int*      dstc    = (int*)     (ws + (size_t)6  * 1024 * 1024);  // E*4
    float*    score_c = (float*)   (ws + (size_t)10 * 1024 * 1024);  // E*4

    hipMemsetAsync(slot, 0xFF, (size_t)N_NODES * 4, stream);
    hipMemsetAsync(ws + 512 * 1024, 0, 1024 * 1024 + 4096, stream);  // segmax+segsum+count
    hipMemsetAsync(out, 0, (size_t)out_size * 4, stream);

    mark_nodes_kernel<<<(B + 255) / 256, 256, 0, stream>>>(nodes, slot, B);

    count_kernel<<<NBLK, 256, 0, stream>>>(dst, slot, bcount, E);
    scan_kernel<<<1, 256, 0, stream>>>(bcount, boff, count, NBLK);
    fill_kernel<<<NBLK, 256, 0, stream>>>(dst, slot, boff, elist, dstc, E);

    mlp_score_kernel<<<1024, 256, 0, stream>>>(embed_u, rep, W1, b1, W2, b2, W3, b3,
                                               count, elist, dstc, score_c, segmax);

    expsum_kernel<<<512, 256, 0, stream>>>(count, dstc, segmax, score_c, segsum);

    agg_kernel<<<2048, 256, 0, stream>>>(embed_u, count, elist, dstc, slot,
                                         score_c, segsum, out);

    repl_kernel<<<(B * D + 255) / 256, 256, 0, stream>>>(nodes, slot, out, B);
}

// Round 4
// 107.791 us; speedup vs baseline: 5.8441x; 1.1565x over previous
//
#include <hip/hip_runtime.h>
#include <math.h>

static constexpr int N_NODES = 100000;
static constexpr int D = 64;
static constexpr int CHUNKN = 4096;            // nodes per scan block
static constexpr int NB2 = (N_NODES + CHUNKN - 1) / CHUNKN;   // 25

typedef float  f32x4 __attribute__((ext_vector_type(4)));
typedef short  s16x8 __attribute__((ext_vector_type(8)));

__device__ __forceinline__ unsigned short f2bf(float f) {
    unsigned u = __float_as_uint(f);
    return (unsigned short)((u + 0x7FFFu + ((u >> 16) & 1u)) >> 16);
}
__device__ __forceinline__ float bf2f(unsigned short s) {
    return __uint_as_float(((unsigned)s) << 16);
}

// Pass 1: slot[node] = min batch index referencing it; 0xFFFFFFFF = not requested.
__global__ void mark_nodes_kernel(const int* __restrict__ nodes,
                                  unsigned* __restrict__ slot, int B) {
    int b = blockIdx.x * blockDim.x + threadIdx.x;
    if (b < B) atomicMin(&slot[nodes[b]], (unsigned)b);
}

// Pass 2: deg[d] = number of flagged edges with dst d.
__global__ void degcount_kernel(const int* __restrict__ dst,
                                const unsigned* __restrict__ slot,
                                unsigned* __restrict__ deg, int E) {
    int e = blockIdx.x * blockDim.x + threadIdx.x;
    if (e >= E) return;
    int d = dst[e];
    if (slot[d] != 0xFFFFFFFFu) atomicAdd(&deg[d], 1u);
}

// Pass 3a: per-block sums over deg: edge total and nonzero-node count.
__global__ __launch_bounds__(256) void nodesum_kernel(
    const unsigned* __restrict__ deg,
    unsigned* __restrict__ nbsum, unsigned* __restrict__ nbnz, int N) {
    const int base = blockIdx.x * CHUNKN;
    unsigned s = 0, z = 0;
    for (int it = 0; it < CHUNKN; it += 256) {
        int i = base + it + threadIdx.x;
        if (i < N) { unsigned v = deg[i]; s += v; z += (v > 0) ? 1u : 0u; }
    }
    #pragma unroll
    for (int off = 32; off; off >>= 1) { s += __shfl_down(s, off); z += __shfl_down(z, off); }
    __shared__ unsigned ws[4], wz[4];
    if ((threadIdx.x & 63) == 0) { ws[threadIdx.x >> 6] = s; wz[threadIdx.x >> 6] = z; }
    __syncthreads();
    if (threadIdx.x == 0) {
        nbsum[blockIdx.x] = ws[0] + ws[1] + ws[2] + ws[3];
        nbnz[blockIdx.x]  = wz[0] + wz[1] + wz[2] + wz[3];
    }
}

// Pass 3b: single-wave exclusive scan of both arrays (n <= 64); total flagged nodes.
__global__ void scan2_kernel(const unsigned* __restrict__ nbsum,
                             const unsigned* __restrict__ nbnz,
                             unsigned* __restrict__ nboff,
                             unsigned* __restrict__ nznoff,
                             unsigned* __restrict__ nflag, int n) {
    int t = threadIdx.x;
    if (t >= 64) return;
    unsigned vE = (t < n) ? nbsum[t] : 0;
    unsigned vZ = (t < n) ? nbnz[t] : 0;
    unsigned pE = vE, pZ = vZ;
    #pragma unroll
    for (int off = 1; off < 64; off <<= 1) {
        unsigned tE = __shfl_up(pE, off), tZ = __shfl_up(pZ, off);
        if (t >= off) { pE += tE; pZ += tZ; }
    }
    if (t < n) { nboff[t] = pE - vE; nznoff[t] = pZ - vZ; }
    if (t == 63) *nflag = pZ;
}

// Pass 3c: csr_off/cursor = exclusive prefix of deg; nlist = compacted flagged nodes.
__global__ __launch_bounds__(256) void csrfill_kernel(
    const unsigned* __restrict__ deg,
    const unsigned* __restrict__ nboff, const unsigned* __restrict__ nznoff,
    unsigned* __restrict__ csr_off, unsigned* __restrict__ cursor,
    int* __restrict__ nlist, int N) {
    __shared__ unsigned runE, runZ, wsE[4], wsZ[4];
    const int base = blockIdx.x * CHUNKN;
    if (threadIdx.x == 0) { runE = nboff[blockIdx.x]; runZ = nznoff[blockIdx.x]; }
    __syncthreads();
    const int lane = threadIdx.x & 63;
    const int w = threadIdx.x >> 6;
    for (int it = 0; it < CHUNKN; it += 256) {
        int i = base + it + threadIdx.x;
        unsigned v = (i < N) ? deg[i] : 0;
        bool nz = v > 0;
        unsigned p = v;
        #pragma unroll
        for (int off = 1; off < 64; off <<= 1) {
            unsigned tp = __shfl_up(p, off);
            if (lane >= off) p += tp;
        }
        unsigned long long m = __ballot(nz);
        unsigned lower = __popcll(m & ((1ull << lane) - 1ull));
        if (lane == 63) { wsE[w] = p; wsZ[w] = (unsigned)__popcll(m); }
        __syncthreads();
        unsigned woffE = 0, woffZ = 0;
        for (int ww = 0; ww < w; ++ww) { woffE += wsE[ww]; woffZ += wsZ[ww]; }
        if (i < N) {
            unsigned off = runE + woffE + p - v;
            csr_off[i] = off;
            cursor[i] = off;
            if (nz) nlist[runZ + woffZ + lower] = i;
        }
        __syncthreads();
        if (threadIdx.x == 0) {
            runE += wsE[0] + wsE[1] + wsE[2] + wsE[3];
            runZ += wsZ[0] + wsZ[1] + wsZ[2] + wsZ[3];
        }
        __syncthreads();
    }
}

// Pass 4: scatter flagged edges into per-dst CSR lists.
__global__ void scatter_kernel(const int* __restrict__ dst,
                               const unsigned* __restrict__ slot,
                               unsigned* __restrict__ cursor,
                               int* __restrict__ cedge, int E) {
    int e = blockIdx.x * blockDim.x + threadIdx.x;
    if (e >= E) return;
    int d = dst[e];
    if (slot[d] != 0xFFFFFFFFu) {
        unsigned pos = atomicAdd(&cursor[d], 1u);
        cedge[pos] = e;
    }
}

// Pass 5: FUSED — wave per destination node: MFMA MLP on 16-edge tiles,
// online softmax across tiles, PV from the staged LDS tile, one output write.
__global__ __launch_bounds__(256) void fused_kernel(
    const float* __restrict__ embed_u, const float* __restrict__ rep,
    const float* __restrict__ W1, const float* __restrict__ b1,
    const float* __restrict__ W2, const float* __restrict__ b2,
    const float* __restrict__ W3,
    const unsigned* __restrict__ nflag_p,
    const int* __restrict__ nlist,
    const unsigned* __restrict__ csr_off, const unsigned* __restrict__ deg,
    const int* __restrict__ cedge,
    const unsigned* __restrict__ slot,
    float* __restrict__ out)
{
    __shared__ __align__(16) short W1t[64 * 136];
    __shared__ __align__(16) short W2t[64 * 72];
    __shared__ __align__(16) short Xbf[4][16 * 136];
    __shared__ __align__(16) short Hs[4][16 * 72];
    __shared__ float scL[4][16];

    const int tid = threadIdx.x;
    for (int i = tid; i < 128 * 64; i += 256) {
        int k = i >> 6, c = i & 63;
        W1t[c * 136 + k] = (short)f2bf(W1[i]);
    }
    for (int i = tid; i < 64 * 64; i += 256) {
        int k = i >> 6, c = i & 63;
        W2t[c * 72 + k] = (short)f2bf(W2[i]);
    }
    __syncthreads();

    const int nflag = (int)*nflag_p;
    const int wid = tid >> 6;
    const int lane = tid & 63;
    const int cl = lane & 15;
    const int quad = lane >> 4;

    float b1v[4], b2v[4], w3v[4];
    #pragma unroll
    for (int ct = 0; ct < 4; ++ct) {
        b1v[ct] = b1[ct * 16 + cl];
        b2v[ct] = b2[ct * 16 + cl];
        w3v[ct] = W3[ct * 16 + cl];
    }

    short* Xw = Xbf[wid];
    short* Hw = Hs[wid];
    float* scl = scL[wid];

    const int gw = (blockIdx.x * 256 + tid) >> 6;
    const int nw = (gridDim.x * 256) >> 6;

    for (int ni = gw; ni < nflag; ni += nw) {
        const int n = nlist[ni];
        const int o = (int)csr_off[n];
        const int dn = (int)deg[n];
        const int ntile = (dn + 15) >> 4;

        float m = -INFINITY, S = 0.f, acc = 0.f;

        for (int t = 0; t < ntile; ++t) {
            const int rem = dn - t * 16;
            const int er = cedge[o + t * 16 + min(cl, rem - 1)];
            const float4* eb = (const float4*)(embed_u + (size_t)er * D);
            const float4* rp = (const float4*)(rep + (size_t)er * D);
            #pragma unroll
            for (int src = 0; src < 2; ++src) {
                const float4* pbase = src ? rp : eb;
                const int kofs = src ? 64 : 0;
                #pragma unroll
                for (int h = 0; h < 2; ++h) {
                    float4 v0 = pbase[quad * 4 + h * 2 + 0];
                    float4 v1 = pbase[quad * 4 + h * 2 + 1];
                    s16x8 pk;
                    pk[0] = (short)f2bf(v0.x); pk[1] = (short)f2bf(v0.y);
                    pk[2] = (short)f2bf(v0.z); pk[3] = (short)f2bf(v0.w);
                    pk[4] = (short)f2bf(v1.x); pk[5] = (short)f2bf(v1.y);
                    pk[6] = (short)f2bf(v1.z); pk[7] = (short)f2bf(v1.w);
                    *(s16x8*)&Xw[cl * 136 + kofs + quad * 16 + h * 8] = pk;
                }
            }

            // layer 1: [16,128] x [128,64]
            f32x4 a1[4];
            #pragma unroll
            for (int ct = 0; ct < 4; ++ct)
                a1[ct] = (f32x4){b1v[ct], b1v[ct], b1v[ct], b1v[ct]};
            #pragma unroll
            for (int ks = 0; ks < 4; ++ks) {
                s16x8 af = *(const s16x8*)&Xw[cl * 136 + ks * 32 + quad * 8];
                #pragma unroll
                for (int ct = 0; ct < 4; ++ct) {
                    s16x8 bf = *(const s16x8*)&W1t[(ct * 16 + cl) * 136 + ks * 32 + quad * 8];
                    a1[ct] = __builtin_amdgcn_mfma_f32_16x16x32_bf16(af, bf, a1[ct], 0, 0, 0);
                }
            }
            #pragma unroll
            for (int ct = 0; ct < 4; ++ct)
                #pragma unroll
                for (int reg = 0; reg < 4; ++reg)
                    Hw[(quad * 4 + reg) * 72 + ct * 16 + cl] =
                        (short)f2bf(fmaxf(a1[ct][reg], 0.f));

            // layer 2: [16,64] x [64,64]
            f32x4 a2[4];
            #pragma unroll
            for (int ct = 0; ct < 4; ++ct)
                a2[ct] = (f32x4){b2v[ct], b2v[ct], b2v[ct], b2v[ct]};
            #pragma unroll
            for (int ks = 0; ks < 2; ++ks) {
                s16x8 af = *(const s16x8*)&Hw[cl * 72 + ks * 32 + quad * 8];
                #pragma unroll
                for (int ct = 0; ct < 4; ++ct) {
                    s16x8 bf = *(const s16x8*)&W2t[(ct * 16 + cl) * 72 + ks * 32 + quad * 8];
                    a2[ct] = __builtin_amdgcn_mfma_f32_16x16x32_bf16(af, bf, a2[ct], 0, 0, 0);
                }
            }

            // layer 3: per-row dot with W3 (b3 cancels in softmax)
            float p[4];
            #pragma unroll
            for (int reg = 0; reg < 4; ++reg) {
                float s = 0.f;
                #pragma unroll
                for (int ct = 0; ct < 4; ++ct)
                    s += fmaxf(a2[ct][reg], 0.f) * w3v[ct];
                p[reg] = s;
            }
            #pragma unroll
            for (int off = 1; off < 16; off <<= 1)
                #pragma unroll
                for (int reg = 0; reg < 4; ++reg)
                    p[reg] += __shfl_xor(p[reg], off);

            if (cl == 0) {
                #pragma unroll
                for (int reg = 0; reg < 4; ++reg) {
                    int row = quad * 4 + reg;
                    scl[row] = (row < rem) ? p[reg] : -INFINITY;
                }
            }
            __builtin_amdgcn_wave_barrier();

            // online softmax update + PV from LDS u-columns (lane = channel)
            float sv[16];
            #pragma unroll
            for (int r = 0; r < 16; ++r) sv[r] = scl[r];
            float tm = sv[0];
            #pragma unroll
            for (int r = 1; r < 16; ++r) tm = fmaxf(tm, sv[r]);
            const float mN = fmaxf(m, tm);
            const float scale = __expf(m - mN);   // 0 when m == -inf
            S *= scale; acc *= scale;
            #pragma unroll
            for (int r = 0; r < 16; ++r) {
                float wgt = __expf(sv[r] - mN);   // 0 for masked rows
                S += wgt;
                acc = fmaf(wgt, bf2f((unsigned short)Xw[r * 136 + lane]), acc);
            }
            m = mN;
            __builtin_amdgcn_wave_barrier();
        }

        const unsigned s = slot[n];
        out[(size_t)s * D + lane] = acc / S;
    }
}

// Pass 6: replicate rows for duplicate batch entries.
__global__ void repl_kernel(const int* __restrict__ nodes,
                            const unsigned* __restrict__ slot,
                            float* __restrict__ out, int B) {
    int t = blockIdx.x * blockDim.x + threadIdx.x;
    int b = t >> 6, lane = t & 63;
    if (b >= B) return;
    unsigned s = slot[nodes[b]];
    if (s != (unsigned)b) out[(size_t)b * D + lane] = out[(size_t)s * D + lane];
}

extern "C" void kernel_launch(void* const* d_in, const int* in_sizes, int n_in,
                              void* d_out, int out_size, void* d_ws, size_t ws_size,
                              hipStream_t stream) {
    const float* embed_u = (const float*)d_in[0];
    const float* rep     = (const float*)d_in[1];
    const int*   dst     = (const int*)d_in[2];
    const int*   nodes   = (const int*)d_in[3];
    const float* W1      = (const float*)d_in[4];
    const float* b1      = (const float*)d_in[5];
    const float* W2      = (const float*)d_in[6];
    const float* b2      = (const float*)d_in[7];
    const float* W3      = (const float*)d_in[8];
    float* out = (float*)d_out;
    const int E = in_sizes[2];
    const int B = in_sizes[3];

    char* ws = (char*)d_ws;
    unsigned* slot    = (unsigned*)(ws);                        // 400 KB
    unsigned* deg     = (unsigned*)(ws + 512 * 1024);           // 400 KB
    unsigned* csr_off = (unsigned*)(ws + 1024 * 1024);          // 400 KB
    unsigned* cursor  = (unsigned*)(ws + 1536 * 1024);          // 400 KB
    unsigned* nbsum   = (unsigned*)(ws + 2048 * 1024);          // small
    unsigned* nbnz    = (unsigned*)(ws + 2048 * 1024 + 1024);
    unsigned* nboff   = (unsigned*)(ws + 2048 * 1024 + 2048);
    unsigned* nznoff  = (unsigned*)(ws + 2048 * 1024 + 3072);
    unsigned* nflag   = (unsigned*)(ws + 2048 * 1024 + 4096);
    int*      nlist   = (int*)     (ws + 2560 * 1024);          // 400 KB
    int*      cedge   = (int*)     (ws + 3072 * 1024);          // up to E*4

    hipMemsetAsync(slot, 0xFF, (size_t)N_NODES * 4, stream);
    hipMemsetAsync(deg, 0, (size_t)N_NODES * 4, stream);
    hipMemsetAsync(out, 0, (size_t)out_size * 4, stream);

    mark_nodes_kernel<<<(B + 255) / 256, 256, 0, stream>>>(nodes, slot, B);
    degcount_kernel<<<(E + 255) / 256, 256, 0, stream>>>(dst, slot, deg, E);
    nodesum_kernel<<<NB2, 256, 0, stream>>>(deg, nbsum, nbnz, N_NODES);
    scan2_kernel<<<1, 64, 0, stream>>>(nbsum, nbnz, nboff, nznoff, nflag, NB2);
    csrfill_kernel<<<NB2, 256, 0, stream>>>(deg, nboff, nznoff, csr_off, cursor,
                                            nlist, N_NODES);
    scatter_kernel<<<(E + 255) / 256, 256, 0, stream>>>(dst, slot, cursor, cedge, E);

    fused_kernel<<<1024, 256, 0, stream>>>(embed_u, rep, W1, b1, W2, b2, W3,
                                           nflag, nlist, csr_off, deg, cedge,
                                           slot, out);

    repl_kernel<<<(B * D + 255) / 256, 256, 0, stream>>>(nodes, slot, out, B);
}